// Round 3
// baseline (248.264 us; speedup 1.0000x reference)
//
#include <hip/hip_runtime.h>

// CNF vector field + exact divergence via bilinear-form trick.
//   dx  = tanh(tanh([x,t]W1+b1)W2+b2)W3+b3, /2
//   div = 0.5 * d1^T (W2 ∘ (W1[:64]^T W3^T)) d2   (G precomputed, batch-free)
// R2: VGPR_Count was 36 (launch_bounds(1024) w/o waves arg -> register
//     starvation -> no latency hiding, VALUBusy 39%). Fix: launch_bounds(1024,4)
//     = 128-VGPR cap at our exact residency, + batched group-of-8 loads.

constexpr int HD = 512;       // hidden
constexpr int DD = 64;        // data dim
constexpr int SB = 8;         // samples per block
constexpr int NB = 2048 / SB; // 256 blocks

// ---------------- G = W2 ∘ (W1[:64]^T @ W3^T) ----------------
__global__ __launch_bounds__(512) void cnf_g_kernel(
    const float* __restrict__ W1, const float* __restrict__ W2,
    const float* __restrict__ W3, float* __restrict__ G)
{
    __shared__ float w1t[64 * 9];   // [i][jl], pad 9
    __shared__ float w3t[64 * 65];  // [ml][i], pad 65
    const int tid = threadIdx.x;
    const int j0 = (blockIdx.x & 63) * 8;
    const int m0 = (blockIdx.x >> 6) * 64;
    {
        int i = tid >> 3, jl = tid & 7;
        w1t[i * 9 + jl] = W1[i * HD + j0 + jl];
    }
    for (int e = tid; e < 64 * 64; e += 512) {
        int ml = e >> 6, i = e & 63;
        w3t[ml * 65 + i] = W3[(m0 + ml) * DD + i];
    }
    __syncthreads();
    const int jl = tid >> 6, ml = tid & 63;
    float s = 0.f;
#pragma unroll
    for (int i = 0; i < 64; ++i)
        s += w1t[i * 9 + jl] * w3t[ml * 65 + i];
    const int j = j0 + jl, m = m0 + ml;
    G[j * HD + m] = W2[j * HD + m] * s;
}

// ---------------- fused MLP + divergence ----------------
// 1024 threads: u = tid&511 (unit), half = tid>>9 (j-range for layer2).
__global__ __launch_bounds__(1024, 4) void cnf_fused_kernel(
    const float* __restrict__ tptr, const float* __restrict__ x,
    const float* __restrict__ W1, const float* __restrict__ b1,
    const float* __restrict__ W2, const float* __restrict__ b2,
    const float* __restrict__ W3, const float* __restrict__ b3,
    const float* __restrict__ G, float* __restrict__ out)
{
    __shared__ float4 xsv[65 * 2];       // [i][s] sample-innermost
    __shared__ float  sbuf[8192];        // 32KB: h1v+d1v -> P partials -> opart
    __shared__ float4 h2v[HD * 2];       // [m][s]
    __shared__ float  divred[8][8];

    float4* h1v = reinterpret_cast<float4*>(sbuf);          // [0..1023]
    float4* d1v = reinterpret_cast<float4*>(sbuf + 4096);   // [0..1023]

    const int tid  = threadIdx.x;
    const int s0   = blockIdx.x * SB;
    const int u    = tid & 511;
    const int half = tid >> 9;

    // ---- phase 0: stage x rows (drop col 64, append t) ----
    {
        const float tval = tptr[0];
        for (int e = tid; e < SB * 65; e += 1024) {
            int s = e / 65, i = e % 65;
            reinterpret_cast<float*>(xsv)[i * SB + s] =
                (i == DD) ? tval : x[(s0 + s) * 65 + i];
        }
    }
    __syncthreads();

    // ---- phase 1: layer 1; thread = (unit u, 4-sample group half) ----
    {
        const float bb = b1[u];
        float2 a0 = make_float2(bb, bb), a1 = make_float2(bb, bb);
        // batched loads: 65 = 8*8 + 1
        for (int ib = 0; ib < 64; ib += 8) {
            float w[8];
#pragma unroll
            for (int q = 0; q < 8; ++q) w[q] = W1[(ib + q) * HD + u];
#pragma unroll
            for (int q = 0; q < 8; ++q) {
                float4 a = xsv[2 * (ib + q) + half];
                a0.x += a.x * w[q]; a0.y += a.y * w[q];
                a1.x += a.z * w[q]; a1.y += a.w * w[q];
            }
        }
        {
            float w = W1[64 * HD + u];
            float4 a = xsv[2 * 64 + half];
            a0.x += a.x * w; a0.y += a.y * w;
            a1.x += a.z * w; a1.y += a.w * w;
        }
        float h0 = tanhf(a0.x), h1_ = tanhf(a0.y), h2_ = tanhf(a1.x), h3 = tanhf(a1.y);
        h1v[2 * u + half] = make_float4(h0, h1_, h2_, h3);
        d1v[2 * u + half] = make_float4(1.f - h0 * h0, 1.f - h1_ * h1_,
                                        1.f - h2_ * h2_, 1.f - h3 * h3);
    }
    __syncthreads();

    // ---- phase 2: layer 2 + div matvec, j-range split across halves ----
    float2 acc[4], vac[4];
    {
        const float bb = (half == 1) ? b2[u] : 0.f;
#pragma unroll
        for (int p = 0; p < 4; ++p) {
            acc[p] = make_float2(bb, bb);
            vac[p] = make_float2(0.f, 0.f);
        }
        const int jb = half * 256;
        const float* W2c = W2 + (size_t)jb * HD + u;
        const float* Gc  = G  + (size_t)jb * HD + u;
        for (int j0i = 0; j0i < 256; j0i += 8) {
            float w[8], g[8];
#pragma unroll
            for (int q = 0; q < 8; ++q) {
                w[q] = W2c[(size_t)(j0i + q) * HD];
                g[q] = Gc[(size_t)(j0i + q) * HD];
            }
#pragma unroll
            for (int q = 0; q < 8; ++q) {
                const int j = jb + j0i + q;
                float4 ha = h1v[2 * j], hb = h1v[2 * j + 1];
                float4 da = d1v[2 * j], db = d1v[2 * j + 1];
                acc[0].x += ha.x * w[q]; acc[0].y += ha.y * w[q];
                acc[1].x += ha.z * w[q]; acc[1].y += ha.w * w[q];
                acc[2].x += hb.x * w[q]; acc[2].y += hb.y * w[q];
                acc[3].x += hb.z * w[q]; acc[3].y += hb.w * w[q];
                vac[0].x += da.x * g[q]; vac[0].y += da.y * g[q];
                vac[1].x += da.z * g[q]; vac[1].y += da.w * g[q];
                vac[2].x += db.x * g[q]; vac[2].y += db.y * g[q];
                vac[3].x += db.z * g[q]; vac[3].y += db.w * g[q];
            }
        }
    }
    __syncthreads();   // all h1v/d1v reads done -> sbuf reusable as P
    {
        float2* P = reinterpret_cast<float2*>(sbuf);   // [8][512] float2
        if (half == 0) {
#pragma unroll
            for (int p = 0; p < 4; ++p) {
                P[p * 512 + u]       = acc[p];
                P[(p + 4) * 512 + u] = vac[p];
            }
        }
        __syncthreads();
        if (half == 1) {
#pragma unroll
            for (int p = 0; p < 4; ++p) {
                float2 pa = P[p * 512 + u], pv = P[(p + 4) * 512 + u];
                acc[p].x += pa.x; acc[p].y += pa.y;
                vac[p].x += pv.x; vac[p].y += pv.y;
            }
            float h[8];
            h[0] = tanhf(acc[0].x); h[1] = tanhf(acc[0].y);
            h[2] = tanhf(acc[1].x); h[3] = tanhf(acc[1].y);
            h[4] = tanhf(acc[2].x); h[5] = tanhf(acc[2].y);
            h[6] = tanhf(acc[3].x); h[7] = tanhf(acc[3].y);
            h2v[2 * u]     = make_float4(h[0], h[1], h[2], h[3]);
            h2v[2 * u + 1] = make_float4(h[4], h[5], h[6], h[7]);
            float vt[8] = {vac[0].x, vac[0].y, vac[1].x, vac[1].y,
                           vac[2].x, vac[2].y, vac[3].x, vac[3].y};
            float dp[8];
#pragma unroll
            for (int q = 0; q < 8; ++q) dp[q] = vt[q] * (1.f - h[q] * h[q]);
#pragma unroll
            for (int q = 0; q < 8; ++q) {
                float v = dp[q];
                for (int off = 32; off > 0; off >>= 1) v += __shfl_down(v, off);
                dp[q] = v;
            }
            const int wv = (tid >> 6) & 7, lane = tid & 63;
            if (lane == 0) {
#pragma unroll
                for (int q = 0; q < 8; ++q) divred[wv][q] = dp[q];
            }
        }
    }
    __syncthreads();   // h2v + divred ready; sbuf free again (opart)
    if (tid < 8) {
        float ds = 0.f;
#pragma unroll
        for (int w = 0; w < 8; ++w) ds += divred[w][tid];
        out[(s0 + tid) * 65 + DD] = 0.5f * ds;
    }

    // ---- phase 4: layer 3; thread = (part<16, k<64), 32 m's per part ----
    {
        const int k = tid & 63, part = tid >> 6;
        float o[8];
#pragma unroll
        for (int q = 0; q < 8; ++q) o[q] = 0.f;
        const int mb = part * 32;
        for (int mm = 0; mm < 32; mm += 8) {
            float w[8];
#pragma unroll
            for (int q = 0; q < 8; ++q) w[q] = W3[(mb + mm + q) * DD + k];
#pragma unroll
            for (int q = 0; q < 8; ++q) {
                const int m = mb + mm + q;
                float4 ha = h2v[2 * m], hb = h2v[2 * m + 1];
                o[0] += ha.x * w[q]; o[1] += ha.y * w[q];
                o[2] += ha.z * w[q]; o[3] += ha.w * w[q];
                o[4] += hb.x * w[q]; o[5] += hb.y * w[q];
                o[6] += hb.z * w[q]; o[7] += hb.w * w[q];
            }
        }
#pragma unroll
        for (int q = 0; q < 8; ++q) sbuf[part * 512 + q * 64 + k] = o[q];
    }
    __syncthreads();
    if (tid < 512) {
        const int s = tid >> 6, k = tid & 63;
        float sum = b3[k];
#pragma unroll
        for (int p = 0; p < 16; ++p) sum += sbuf[p * 512 + s * 64 + k];
        out[(s0 + s) * 65 + k] = 0.5f * sum;
    }
}

extern "C" void kernel_launch(void* const* d_in, const int* in_sizes, int n_in,
                              void* d_out, int out_size, void* d_ws, size_t ws_size,
                              hipStream_t stream) {
    const float* t  = (const float*)d_in[0];
    const float* x  = (const float*)d_in[1];
    const float* W1 = (const float*)d_in[2];
    const float* b1 = (const float*)d_in[3];
    const float* W2 = (const float*)d_in[4];
    const float* b2 = (const float*)d_in[5];
    const float* W3 = (const float*)d_in[6];
    const float* b3 = (const float*)d_in[7];
    float* out = (float*)d_out;
    float* G   = (float*)d_ws;             // 512*512*4 = 1 MB scratch

    cnf_g_kernel<<<512, 512, 0, stream>>>(W1, W2, W3, G);
    cnf_fused_kernel<<<NB, 1024, 0, stream>>>(t, x, W1, b1, W2, b2, W3, b3, G, out);
}